// Round 4
// baseline (1256.481 us; speedup 1.0000x reference)
//
#include <hip/hip_runtime.h>
#include <hip/hip_bf16.h>

using bf16 = __bf16;
typedef __bf16 bf16x8 __attribute__((ext_vector_type(8)));
typedef float  f32x4  __attribute__((ext_vector_type(4)));

// ---------------------------------------------------------------------------
// Weight transpose + downcast: Wt[n*ldT + k] = (bf16)W[k*N + n]  (fp32 KxN in)
// Coalesced writes along k; reads strided but tiny (<10 MB, L2-absorbed).
// ---------------------------------------------------------------------------
__global__ void transpose_k(const float* __restrict__ W, bf16* __restrict__ Wt,
                            int K, int N, int ldT, int total)
{
    int idx = blockIdx.x * 256 + threadIdx.x;
    if (idx >= total) return;
    int k = idx % K;
    int n = idx / K;
    Wt[(size_t)n * ldT + k] = (bf16)W[(size_t)k * N + n];
}

// ---------------------------------------------------------------------------
// MFMA GEMM: C(MxN) = A(MxK) * B(KxN), B given transposed (Bt: N x K bf16).
// 128x128 tile, BK=32, 4 waves, each 64x64 (4x4 x 16x16x32 MFMA).
// AMODE 0: A bf16, row stride K (direct).
// AMODE 1: A fp32, row stride K (downcast during staging).
// AMODE 2 (KAN): A fp32 x with row stride 512; logical A = [swish(x)|phi(x)]:
//   k <  512 : swish(x[m][k])
//   k >= 512 : phi, channel c=(k-512)/5, gauss g=(k-512)%5, grid pt g-2, h=1.
// CT: output element type (bf16 for intermediates, float for final d_out).
// ---------------------------------------------------------------------------
template<int AMODE, bool BIAS, typename CT>
__global__ __launch_bounds__(256, 2)
void gemm_bt(const void* __restrict__ Avoid, const bf16* __restrict__ Bt,
             CT* __restrict__ C, int M, int N, int K,
             const float* __restrict__ bias)
{
    constexpr int LDA = 40;              // 32 + 8 pad: 16B-aligned rows, breaks pow2 stride
    __shared__ bf16 As[128 * LDA];
    __shared__ bf16 Bs[128 * LDA];

    const int tid  = threadIdx.x;
    const int lane = tid & 63;
    const int wave = tid >> 6;
    const int quad = lane >> 4;
    const int l15  = lane & 15;
    const int wr = wave >> 1, wc = wave & 1;
    const int m0 = blockIdx.y * 128, n0 = blockIdx.x * 128;

    f32x4 acc[4][4] = {};

    for (int kt = 0; kt < K; kt += 32) {
#pragma unroll
        for (int cc = 0; cc < 2; ++cc) {
            const int chunk = cc * 256 + tid;     // 512 chunks of 8 bf16
            const int row   = chunk >> 2;         // 0..127
            const int col8  = (chunk & 3) * 8;    // 0,8,16,24

            // ---- B tile ----
            *(bf16x8*)(Bs + row * LDA + col8) =
                *(const bf16x8*)(Bt + (size_t)(n0 + row) * K + kt + col8);

            // ---- A tile ----
            if (AMODE == 0) {
                const bf16* A = (const bf16*)Avoid;
                *(bf16x8*)(As + row * LDA + col8) =
                    *(const bf16x8*)(A + (size_t)(m0 + row) * K + kt + col8);
            } else if (AMODE == 1) {
                const float* A = (const float*)Avoid;
                float4 a = *(const float4*)(A + (size_t)(m0 + row) * K + kt + col8);
                float4 b = *(const float4*)(A + (size_t)(m0 + row) * K + kt + col8 + 4);
                bf16x8 o;
                o[0] = (bf16)a.x; o[1] = (bf16)a.y; o[2] = (bf16)a.z; o[3] = (bf16)a.w;
                o[4] = (bf16)b.x; o[5] = (bf16)b.y; o[6] = (bf16)b.z; o[7] = (bf16)b.w;
                *(bf16x8*)(As + row * LDA + col8) = o;
            } else {
                const float* X = (const float*)Avoid;   // row stride 512
                const int kg = kt + col8;
                bf16x8 o;
                if (kg < 512) {
                    float4 a = *(const float4*)(X + (size_t)(m0 + row) * 512 + kg);
                    float4 b = *(const float4*)(X + (size_t)(m0 + row) * 512 + kg + 4);
                    float xs[8] = {a.x, a.y, a.z, a.w, b.x, b.y, b.z, b.w};
#pragma unroll
                    for (int t = 0; t < 8; ++t)
                        o[t] = (bf16)(xs[t] / (1.0f + __expf(-xs[t])));
                } else {
                    const int ks = kg - 512;
                    const float* xrow = X + (size_t)(m0 + row) * 512;
#pragma unroll
                    for (int t = 0; t < 8; ++t) {
                        int kk = ks + t;
                        int c  = kk / 5;
                        int g  = kk - c * 5;
                        float xv = xrow[c];
                        float d  = xv - (float)(g - 2);
                        o[t] = (bf16)__expf(-d * d);
                    }
                }
                *(bf16x8*)(As + row * LDA + col8) = o;
            }
        }
        __syncthreads();

        bf16x8 af[4], bfr[4];
#pragma unroll
        for (int i = 0; i < 4; ++i)
            af[i] = *(const bf16x8*)(As + (wr * 64 + i * 16 + l15) * LDA + quad * 8);
#pragma unroll
        for (int j = 0; j < 4; ++j)
            bfr[j] = *(const bf16x8*)(Bs + (wc * 64 + j * 16 + l15) * LDA + quad * 8);
#pragma unroll
        for (int i = 0; i < 4; ++i)
#pragma unroll
            for (int j = 0; j < 4; ++j)
                acc[i][j] = __builtin_amdgcn_mfma_f32_16x16x32_bf16(af[i], bfr[j], acc[i][j], 0, 0, 0);
        __syncthreads();
    }

    // Epilogue: D layout col=lane&15, row=quad*4+reg
#pragma unroll
    for (int i = 0; i < 4; ++i) {
#pragma unroll
        for (int j = 0; j < 4; ++j) {
            const int col = n0 + wc * 64 + j * 16 + l15;
            const float bv = BIAS ? bias[col] : 0.0f;
#pragma unroll
            for (int r = 0; r < 4; ++r) {
                const int row = m0 + wr * 64 + i * 16 + quad * 4 + r;
                C[(size_t)row * N + col] = (CT)(acc[i][j][r] + bv);
            }
        }
    }
}

// ---------------------------------------------------------------------------
// Attention: one block per (window b, head h). q/k/v: [B*64, 512] bf16,
// head slice h*32..h*32+31. S = qk^T*scale + bias[relidx], softmax rows,
// ctx = S*v. ctx aliases q (each block reads exactly the slice it writes;
// reads complete before writes; other blocks touch disjoint slices).
// ---------------------------------------------------------------------------
__global__ __launch_bounds__(256)
void attn_kernel(const bf16* q, const bf16* __restrict__ k,
                 const bf16* __restrict__ v, const float* __restrict__ bias_table,
                 bf16* ctx)
{
    __shared__ float qs[64][33];
    __shared__ float ks[64][33];
    __shared__ float vs[64][33];
    __shared__ float S[64][65];

    const int bid = blockIdx.x;
    const int b = bid >> 4;
    const int h = bid & 15;
    const int tid = threadIdx.x;
    const int n  = tid >> 2;
    const int d0 = (tid & 3) * 8;
    const size_t base = ((size_t)(b * 64 + n)) * 512 + h * 32 + d0;

    {
        bf16x8 rq = *(const bf16x8*)(q + base);
        bf16x8 rk = *(const bf16x8*)(k + base);
        bf16x8 rv = *(const bf16x8*)(v + base);
#pragma unroll
        for (int t = 0; t < 8; ++t) {
            qs[n][d0 + t] = (float)rq[t];
            ks[n][d0 + t] = (float)rk[t];
            vs[n][d0 + t] = (float)rv[t];
        }
    }
    __syncthreads();

    {
        const int r  = tid >> 2;
        const int c0 = (tid & 3) * 16;
        const int rh = r >> 3, rw = r & 7;
        const float scale = 0.17677669529663687f;   // 1/sqrt(32)
#pragma unroll 4
        for (int cc = 0; cc < 16; ++cc) {
            const int c = c0 + cc;
            float s = 0.0f;
#pragma unroll
            for (int d = 0; d < 32; ++d) s += qs[r][d] * ks[c][d];
            const int ch = c >> 3, cw = c & 7;
            const int idx = (rh - ch + 7) * 15 + (rw - cw + 7);
            S[r][c] = s * scale + bias_table[idx * 16 + h];
        }
    }
    __syncthreads();

    if (tid < 64) {
        float m = -1e30f;
        for (int c = 0; c < 64; ++c) m = fmaxf(m, S[tid][c]);
        float sum = 0.0f;
        for (int c = 0; c < 64; ++c) { float e = __expf(S[tid][c] - m); S[tid][c] = e; sum += e; }
        float inv = 1.0f / sum;
        for (int c = 0; c < 64; ++c) S[tid][c] *= inv;
    }
    __syncthreads();

    {
        const int r = tid >> 2;
        float o[8] = {};
        for (int m = 0; m < 64; ++m) {
            const float sm = S[r][m];
#pragma unroll
            for (int t = 0; t < 8; ++t) o[t] += sm * vs[m][d0 + t];
        }
        bf16x8 ov;
#pragma unroll
        for (int t = 0; t < 8; ++t) ov[t] = (bf16)o[t];
        *(bf16x8*)(ctx + base) = ov;
    }
}

// ---------------------------------------------------------------------------
// ws layout (bf16 elements) — total 35,913,728 elems = 68.5 MiB:
//   0         WqT     512*512
//   262144    WvT     512*512
//   524288    WprojT  512*512
//   786432    WkT     512*3072  (row n = [Wk_base[:,n] | Wk_spline[:,n]])
//   2359296   q/ctx   32768*512
//   19136512  k       32768*512
// v (bf16, 33.5 MB) lives in d_out (fp32 buffer, 67 MB): dead after attn;
// the final GEMM then rewrites all of d_out with fp32 output.
// ---------------------------------------------------------------------------
extern "C" void kernel_launch(void* const* d_in, const int* in_sizes, int n_in,
                              void* d_out, int out_size, void* d_ws, size_t ws_size,
                              hipStream_t stream)
{
    const float* x       = (const float*)d_in[0];
    const float* Wq      = (const float*)d_in[1];
    const float* Wk_base = (const float*)d_in[2];
    const float* Wk_spl  = (const float*)d_in[3];
    const float* Wv      = (const float*)d_in[4];
    const float* Wproj   = (const float*)d_in[5];
    const float* bproj   = (const float*)d_in[6];
    const float* btab    = (const float*)d_in[7];

    bf16* ws  = (bf16*)d_ws;
    bf16* wqT = ws;
    bf16* wvT = ws + 262144;
    bf16* wpT = ws + 524288;
    bf16* wkT = ws + 786432;
    bf16* q   = ws + 2359296;
    bf16* kk  = q + 16777216;
    bf16* vv  = (bf16*)d_out;     // v scratch in d_out (rewritten later)
    bf16* ctx = q;                // reuse q

    transpose_k<<<1024, 256, 0, stream>>>(Wq,      wqT,       512,  512, 512,  262144);
    transpose_k<<<1024, 256, 0, stream>>>(Wv,      wvT,       512,  512, 512,  262144);
    transpose_k<<<1024, 256, 0, stream>>>(Wproj,   wpT,       512,  512, 512,  262144);
    transpose_k<<<1024, 256, 0, stream>>>(Wk_base, wkT,       512,  512, 3072, 262144);
    transpose_k<<<5120, 256, 0, stream>>>(Wk_spl,  wkT + 512, 2560, 512, 3072, 1310720);

    dim3 ggrid(4, 256);  // N/128 x M/128
    gemm_bt<1, false, bf16><<<ggrid, 256, 0, stream>>>(x,   wqT, q,  32768, 512, 512,  nullptr);
    gemm_bt<2, false, bf16><<<ggrid, 256, 0, stream>>>(x,   wkT, kk, 32768, 512, 3072, nullptr);
    gemm_bt<1, false, bf16><<<ggrid, 256, 0, stream>>>(x,   wvT, vv, 32768, 512, 512,  nullptr);

    attn_kernel<<<8192, 256, 0, stream>>>(q, kk, vv, btab, ctx);

    gemm_bt<0, true, float><<<ggrid, 256, 0, stream>>>(ctx, wpT, (float*)d_out, 32768, 512, 512, bproj);
}

// Round 5
// 646.638 us; speedup vs baseline: 1.9431x; 1.9431x over previous
//
#include <hip/hip_runtime.h>
#include <hip/hip_bf16.h>

using bf16 = __bf16;
typedef __bf16 bf16x8 __attribute__((ext_vector_type(8)));
typedef float  f32x4  __attribute__((ext_vector_type(4)));

// ---------------------------------------------------------------------------
// Prep: one pass over fp32 x -> xb = (bf16)x  and  swb = (bf16)swish(x).
// ---------------------------------------------------------------------------
__global__ void prep(const float* __restrict__ x, bf16* __restrict__ xb,
                     bf16* __restrict__ swb, int n)
{
    int base = (blockIdx.x * 256 + threadIdx.x) * 8;
    if (base >= n) return;
    float4 a = *(const float4*)(x + base);
    float4 b = *(const float4*)(x + base + 4);
    float xs[8] = {a.x, a.y, a.z, a.w, b.x, b.y, b.z, b.w};
    bf16x8 xo, so;
#pragma unroll
    for (int t = 0; t < 8; ++t) {
        xo[t] = (bf16)xs[t];
        so[t] = (bf16)(xs[t] / (1.0f + __expf(-xs[t])));
    }
    *(bf16x8*)(xb  + base) = xo;
    *(bf16x8*)(swb + base) = so;
}

// ---------------------------------------------------------------------------
// Weight transpose + downcast: Wt[n*ldT + k] = (bf16)W[k*N + n]  (fp32 KxN in)
// ---------------------------------------------------------------------------
__global__ void transpose_k(const float* __restrict__ W, bf16* __restrict__ Wt,
                            int K, int N, int ldT, int total)
{
    int idx = blockIdx.x * 256 + threadIdx.x;
    if (idx >= total) return;
    int k = idx % K;
    int n = idx / K;
    Wt[(size_t)n * ldT + k] = (bf16)W[(size_t)k * N + n];
}

// ---------------------------------------------------------------------------
// MFMA GEMM: C(MxN) = A(MxK) * B(KxN), B transposed (Bt: N x K bf16).
// 128x128 tile, BK=32, 4 waves, each 64x64 (4x4 x 16x16x32 MFMA).
// AMODE 0: A bf16, row stride K (direct).   X unused.
// AMODE 2 (KAN): logical A = [swish(x) | phi(x)], K=3072:
//   k <  512 : direct bf16x8 from A = swb (row stride 512).
//   k >= 512 : phi from X = fp32 x (row stride 512): channel c=(k-512)/5,
//              gauss g=(k-512)%5, phi = exp(-(x[c]-(g-2))^2).  Each 8-wide
//              chunk spans <=3 channels -> 3 scalar L2-hit loads + shift reg.
// CT: output element type (bf16 intermediates, float for final d_out).
// ---------------------------------------------------------------------------
template<int AMODE, bool BIAS, typename CT>
__global__ __launch_bounds__(256, 2)
void gemm_bt(const bf16* __restrict__ A, const float* __restrict__ X,
             const bf16* __restrict__ Bt, CT* __restrict__ C,
             int M, int N, int K, const float* __restrict__ bias)
{
    constexpr int LDA = 40;              // 32 + 8 pad: 16B-aligned rows, breaks pow2 stride
    __shared__ bf16 As[128 * LDA];
    __shared__ bf16 Bs[128 * LDA];

    const int tid  = threadIdx.x;
    const int lane = tid & 63;
    const int wave = tid >> 6;
    const int quad = lane >> 4;
    const int l15  = lane & 15;
    const int wr = wave >> 1, wc = wave & 1;
    const int m0 = blockIdx.y * 128, n0 = blockIdx.x * 128;

    f32x4 acc[4][4] = {};

    for (int kt = 0; kt < K; kt += 32) {
#pragma unroll
        for (int cc = 0; cc < 2; ++cc) {
            const int chunk = cc * 256 + tid;     // 512 chunks of 8 bf16
            const int row   = chunk >> 2;         // 0..127
            const int col8  = (chunk & 3) * 8;    // 0,8,16,24

            // ---- B tile ----
            *(bf16x8*)(Bs + row * LDA + col8) =
                *(const bf16x8*)(Bt + (size_t)(n0 + row) * K + kt + col8);

            // ---- A tile ----
            if (AMODE == 0) {
                *(bf16x8*)(As + row * LDA + col8) =
                    *(const bf16x8*)(A + (size_t)(m0 + row) * K + kt + col8);
            } else {
                const int kg = kt + col8;
                if (kg < 512) {
                    // swish precomputed (bf16), row stride 512
                    *(bf16x8*)(As + row * LDA + col8) =
                        *(const bf16x8*)(A + (size_t)(m0 + row) * 512 + kg);
                } else {
                    const int ks = kg - 512;          // 0..2552 for chunk starts
                    const int c0 = ks / 5;
                    const int r0 = ks - c0 * 5;
                    const float* xr = X + (size_t)(m0 + row) * 512 + c0;
                    const float x0 = xr[0];
                    const float x1 = xr[1];
                    // 3rd channel only ever needed when c0 <= 509 (proof: if
                    // r0 >= 3 then ks <= 2552 forces c0 <= 509). Clamp keeps
                    // the load in-bounds of x at the buffer tail.
                    const float x2v = xr[(c0 < 510) ? 2 : 1];
                    bf16x8 o;
                    float xv = x0, xnext = x1;
                    int g = r0;
#pragma unroll
                    for (int t = 0; t < 8; ++t) {
                        float d = xv - (float)(g - 2);
                        o[t] = (bf16)__expf(-d * d);
                        if (++g == 5) { g = 0; xv = xnext; xnext = x2v; }
                    }
                    *(bf16x8*)(As + row * LDA + col8) = o;
                }
            }
        }
        __syncthreads();

        bf16x8 af[4], bfr[4];
#pragma unroll
        for (int i = 0; i < 4; ++i)
            af[i] = *(const bf16x8*)(As + (wr * 64 + i * 16 + l15) * LDA + quad * 8);
#pragma unroll
        for (int j = 0; j < 4; ++j)
            bfr[j] = *(const bf16x8*)(Bs + (wc * 64 + j * 16 + l15) * LDA + quad * 8);
#pragma unroll
        for (int i = 0; i < 4; ++i)
#pragma unroll
            for (int j = 0; j < 4; ++j)
                acc[i][j] = __builtin_amdgcn_mfma_f32_16x16x32_bf16(af[i], bfr[j], acc[i][j], 0, 0, 0);
        __syncthreads();
    }

    // Epilogue: D layout col=lane&15, row=quad*4+reg
#pragma unroll
    for (int i = 0; i < 4; ++i) {
#pragma unroll
        for (int j = 0; j < 4; ++j) {
            const int col = n0 + wc * 64 + j * 16 + l15;
            const float bv = BIAS ? bias[col] : 0.0f;
#pragma unroll
            for (int r = 0; r < 4; ++r) {
                const int row = m0 + wr * 64 + i * 16 + quad * 4 + r;
                C[(size_t)row * N + col] = (CT)(acc[i][j][r] + bv);
            }
        }
    }
}

// ---------------------------------------------------------------------------
// Attention: one block per (window b, head h). q/k/v: [B*64, 512] bf16,
// head slice h*32..h*32+31. S = qk^T*scale + bias[relidx], softmax rows,
// ctx = S*v. ctx aliases q (each block reads exactly the slice it writes;
// reads complete before writes; other blocks touch disjoint slices).
// ---------------------------------------------------------------------------
__global__ __launch_bounds__(256)
void attn_kernel(const bf16* q, const bf16* __restrict__ k,
                 const bf16* __restrict__ v, const float* __restrict__ bias_table,
                 bf16* ctx)
{
    __shared__ float qs[64][33];
    __shared__ float ks[64][33];
    __shared__ float vs[64][33];
    __shared__ float S[64][65];

    const int bid = blockIdx.x;
    const int b = bid >> 4;
    const int h = bid & 15;
    const int tid = threadIdx.x;
    const int n  = tid >> 2;
    const int d0 = (tid & 3) * 8;
    const size_t base = ((size_t)(b * 64 + n)) * 512 + h * 32 + d0;

    {
        bf16x8 rq = *(const bf16x8*)(q + base);
        bf16x8 rk = *(const bf16x8*)(k + base);
        bf16x8 rv = *(const bf16x8*)(v + base);
#pragma unroll
        for (int t = 0; t < 8; ++t) {
            qs[n][d0 + t] = (float)rq[t];
            ks[n][d0 + t] = (float)rk[t];
            vs[n][d0 + t] = (float)rv[t];
        }
    }
    __syncthreads();

    {
        const int r  = tid >> 2;
        const int c0 = (tid & 3) * 16;
        const int rh = r >> 3, rw = r & 7;
        const float scale = 0.17677669529663687f;   // 1/sqrt(32)
#pragma unroll 4
        for (int cc = 0; cc < 16; ++cc) {
            const int c = c0 + cc;
            float s = 0.0f;
#pragma unroll
            for (int d = 0; d < 32; ++d) s += qs[r][d] * ks[c][d];
            const int ch = c >> 3, cw = c & 7;
            const int idx = (rh - ch + 7) * 15 + (rw - cw + 7);
            S[r][c] = s * scale + bias_table[idx * 16 + h];
        }
    }
    __syncthreads();

    if (tid < 64) {
        float m = -1e30f;
        for (int c = 0; c < 64; ++c) m = fmaxf(m, S[tid][c]);
        float sum = 0.0f;
        for (int c = 0; c < 64; ++c) { float e = __expf(S[tid][c] - m); S[tid][c] = e; sum += e; }
        float inv = 1.0f / sum;
        for (int c = 0; c < 64; ++c) S[tid][c] *= inv;
    }
    __syncthreads();

    {
        const int r = tid >> 2;
        float o[8] = {};
        for (int m = 0; m < 64; ++m) {
            const float sm = S[r][m];
#pragma unroll
            for (int t = 0; t < 8; ++t) o[t] += sm * vs[m][d0 + t];
        }
        bf16x8 ov;
#pragma unroll
        for (int t = 0; t < 8; ++t) ov[t] = (bf16)o[t];
        *(bf16x8*)(ctx + base) = ov;
    }
}

// ---------------------------------------------------------------------------
// ws layout (bf16 elements) — total 52,690,944 elems = 105.4 MB
// (<= 138.9 MB proven safe by rounds 2/3 bit-identical outputs):
//   0         WqT     512*512
//   262144    WvT     512*512
//   524288    WprojT  512*512
//   786432    WkT     512*3072  (row n = [Wk_base[:,n] | Wk_spline[:,n]])
//   2359296   xb      32768*512 (bf16 x; 1-elem tail overrun lands in q: ok)
//   19136512  q/ctx   32768*512
//   35913728  k       32768*512
// d_out (fp32, 67 MB) doubles as scratch: lower half swb (bf16 swish(x)),
// upper half v (bf16). Both dead before the final GEMM rewrites d_out.
// ---------------------------------------------------------------------------
extern "C" void kernel_launch(void* const* d_in, const int* in_sizes, int n_in,
                              void* d_out, int out_size, void* d_ws, size_t ws_size,
                              hipStream_t stream)
{
    const float* x       = (const float*)d_in[0];
    const float* Wq      = (const float*)d_in[1];
    const float* Wk_base = (const float*)d_in[2];
    const float* Wk_spl  = (const float*)d_in[3];
    const float* Wv      = (const float*)d_in[4];
    const float* Wproj   = (const float*)d_in[5];
    const float* bproj   = (const float*)d_in[6];
    const float* btab    = (const float*)d_in[7];

    bf16* ws  = (bf16*)d_ws;
    bf16* wqT = ws;
    bf16* wvT = ws + 262144;
    bf16* wpT = ws + 524288;
    bf16* wkT = ws + 786432;
    bf16* xb  = ws + 2359296;
    bf16* q   = ws + 19136512;
    bf16* kk  = ws + 35913728;
    bf16* swb = (bf16*)d_out;              // lower half of d_out
    bf16* vv  = (bf16*)d_out + 16777216;   // upper half of d_out
    bf16* ctx = q;                         // reuse q

    prep<<<8192, 256, 0, stream>>>(x, xb, swb, 16777216);

    transpose_k<<<1024, 256, 0, stream>>>(Wq,      wqT,       512,  512, 512,  262144);
    transpose_k<<<1024, 256, 0, stream>>>(Wv,      wvT,       512,  512, 512,  262144);
    transpose_k<<<1024, 256, 0, stream>>>(Wproj,   wpT,       512,  512, 512,  262144);
    transpose_k<<<1024, 256, 0, stream>>>(Wk_base, wkT,       512,  512, 3072, 262144);
    transpose_k<<<5120, 256, 0, stream>>>(Wk_spl,  wkT + 512, 2560, 512, 3072, 1310720);

    dim3 ggrid(4, 256);  // N/128 x M/128
    gemm_bt<0, false, bf16><<<ggrid, 256, 0, stream>>>(xb,  nullptr, wqT, q,  32768, 512, 512,  nullptr);
    gemm_bt<2, false, bf16><<<ggrid, 256, 0, stream>>>(swb, x,       wkT, kk, 32768, 512, 3072, nullptr);
    gemm_bt<0, false, bf16><<<ggrid, 256, 0, stream>>>(xb,  nullptr, wvT, vv, 32768, 512, 512,  nullptr);

    attn_kernel<<<8192, 256, 0, stream>>>(q, kk, vv, btab, ctx);

    gemm_bt<0, true, float><<<ggrid, 256, 0, stream>>>(ctx, nullptr, wpT, (float*)d_out, 32768, 512, 512, bproj);
}

// Round 6
// 611.825 us; speedup vs baseline: 2.0537x; 1.0569x over previous
//
#include <hip/hip_runtime.h>
#include <hip/hip_bf16.h>

using bf16 = __bf16;
typedef __bf16 bf16x8 __attribute__((ext_vector_type(8)));
typedef float  f32x4  __attribute__((ext_vector_type(4)));

// ---------------------------------------------------------------------------
// Prep: one pass over fp32 x -> xb = (bf16)x  and  swb = (bf16)swish(x).
// ---------------------------------------------------------------------------
__global__ void prep(const float* __restrict__ x, bf16* __restrict__ xb,
                     bf16* __restrict__ swb, int n)
{
    int base = (blockIdx.x * 256 + threadIdx.x) * 8;
    if (base >= n) return;
    float4 a = *(const float4*)(x + base);
    float4 b = *(const float4*)(x + base + 4);
    float xs[8] = {a.x, a.y, a.z, a.w, b.x, b.y, b.z, b.w};
    bf16x8 xo, so;
#pragma unroll
    for (int t = 0; t < 8; ++t) {
        xo[t] = (bf16)xs[t];
        so[t] = (bf16)(xs[t] / (1.0f + __expf(-xs[t])));
    }
    *(bf16x8*)(xb  + base) = xo;
    *(bf16x8*)(swb + base) = so;
}

// ---------------------------------------------------------------------------
// Weight transpose + downcast: Wt[n*ldT + k] = (bf16)W[k*N + n]  (fp32 KxN in)
// ---------------------------------------------------------------------------
__global__ void transpose_k(const float* __restrict__ W, bf16* __restrict__ Wt,
                            int K, int N, int ldT, int total)
{
    int idx = blockIdx.x * 256 + threadIdx.x;
    if (idx >= total) return;
    int k = idx % K;
    int n = idx / K;
    Wt[(size_t)n * ldT + k] = (bf16)W[(size_t)k * N + n];
}

// ---------------------------------------------------------------------------
// MFMA GEMM, full-N tiling: C(Mx512) = A(MxK) * B(Kx512), Bt: 512 x K bf16.
// Tile 64(M) x 512(N=全), BK=32, 512 threads = 8 waves; wave w computes the
// 64x64 subtile at columns w*64 (4x4 accs of 16x16x32 MFMA). One N-sweep:
// A (and KAN phi expansion) touched exactly once per element.
// AMODE 0: A bf16, row stride K (direct).  X unused.
// AMODE 2 (KAN): logical A = [swish(x) | phi(x)], K=3072:
//   k <  512 : direct bf16x8 from A = swb (row stride 512).
//   k >= 512 : phi from X = fp32 x (row stride 512): channel c=(k-512)/5,
//              gauss g=(k-512)%5, phi = exp(-(x[c]-(g-2))^2); 8-wide chunk
//              spans <=3 channels -> 3 scalar loads + shift-register eval.
// CT: output element type (bf16 intermediates, float for final d_out).
// ---------------------------------------------------------------------------
template<int AMODE, bool BIAS, typename CT>
__global__ __launch_bounds__(512, 4)
void gemm_bt(const bf16* __restrict__ A, const float* __restrict__ X,
             const bf16* __restrict__ Bt, CT* __restrict__ C,
             int M, int K, const float* __restrict__ bias)
{
    constexpr int LDA = 40;              // 32 + 8 pad: 16B-aligned rows, breaks pow2 stride
    __shared__ bf16 As[64 * LDA];
    __shared__ bf16 Bs[512 * LDA];

    const int tid  = threadIdx.x;
    const int lane = tid & 63;
    const int wave = tid >> 6;
    const int quad = lane >> 4;
    const int l15  = lane & 15;
    const int m0   = blockIdx.x * 64;

    f32x4 acc[4][4] = {};

    for (int kt = 0; kt < K; kt += 32) {
        // ---- B tile: 512 rows x 32k = 2048 chunks of 8 bf16, 4 per thread ----
#pragma unroll
        for (int cc = 0; cc < 4; ++cc) {
            const int chunk = cc * 512 + tid;
            const int row   = chunk >> 2;
            const int col8  = (chunk & 3) * 8;
            *(bf16x8*)(Bs + row * LDA + col8) =
                *(const bf16x8*)(Bt + (size_t)row * K + kt + col8);
        }
        // ---- A tile: 64 rows x 32k = 256 chunks, on waves 0..3 ----
        if (tid < 256) {
            const int row  = tid >> 2;         // 0..63
            const int col8 = (tid & 3) * 8;
            if (AMODE == 0) {
                *(bf16x8*)(As + row * LDA + col8) =
                    *(const bf16x8*)(A + (size_t)(m0 + row) * K + kt + col8);
            } else {
                const int kg = kt + col8;
                if (kg < 512) {
                    *(bf16x8*)(As + row * LDA + col8) =
                        *(const bf16x8*)(A + (size_t)(m0 + row) * 512 + kg);
                } else {
                    const int ks = kg - 512;          // chunk starts 0..2552
                    const int c0 = ks / 5;
                    const int r0 = ks - c0 * 5;
                    const float* xr = X + (size_t)(m0 + row) * 512 + c0;
                    const float x0 = xr[0];
                    const float x1 = xr[1];
                    // 3rd channel only needed when c0 <= 509; clamp keeps the
                    // load in-bounds at the buffer tail (value then unused).
                    const float x2v = xr[(c0 < 510) ? 2 : 1];
                    bf16x8 o;
                    float xv = x0, xnext = x1;
                    int g = r0;
#pragma unroll
                    for (int t = 0; t < 8; ++t) {
                        float d = xv - (float)(g - 2);
                        o[t] = (bf16)__expf(-d * d);
                        if (++g == 5) { g = 0; xv = xnext; xnext = x2v; }
                    }
                    *(bf16x8*)(As + row * LDA + col8) = o;
                }
            }
        }
        __syncthreads();

        bf16x8 af[4], bfr[4];
#pragma unroll
        for (int i = 0; i < 4; ++i)
            af[i] = *(const bf16x8*)(As + (i * 16 + l15) * LDA + quad * 8);
#pragma unroll
        for (int j = 0; j < 4; ++j)
            bfr[j] = *(const bf16x8*)(Bs + (wave * 64 + j * 16 + l15) * LDA + quad * 8);
#pragma unroll
        for (int i = 0; i < 4; ++i)
#pragma unroll
            for (int j = 0; j < 4; ++j)
                acc[i][j] = __builtin_amdgcn_mfma_f32_16x16x32_bf16(af[i], bfr[j], acc[i][j], 0, 0, 0);
        __syncthreads();
    }

    // Epilogue: D layout col=lane&15, row=quad*4+reg
#pragma unroll
    for (int i = 0; i < 4; ++i) {
#pragma unroll
        for (int j = 0; j < 4; ++j) {
            const int col = wave * 64 + j * 16 + l15;
            const float bv = BIAS ? bias[col] : 0.0f;
#pragma unroll
            for (int r = 0; r < 4; ++r) {
                const int row = m0 + i * 16 + quad * 4 + r;
                C[(size_t)row * 512 + col] = (CT)(acc[i][j][r] + bv);
            }
        }
    }
}

// ---------------------------------------------------------------------------
// Attention: one block per (window b, head h). q/k/v: [B*64, 512] bf16,
// head slice h*32..h*32+31. S = qk^T*scale + bias[relidx], softmax rows,
// ctx = S*v. ctx aliases q (each block reads exactly the slice it writes;
// reads complete before writes; other blocks touch disjoint slices).
// ---------------------------------------------------------------------------
__global__ __launch_bounds__(256)
void attn_kernel(const bf16* q, const bf16* __restrict__ k,
                 const bf16* __restrict__ v, const float* __restrict__ bias_table,
                 bf16* ctx)
{
    __shared__ float qs[64][33];
    __shared__ float ks[64][33];
    __shared__ float vs[64][33];
    __shared__ float S[64][65];

    const int bid = blockIdx.x;
    const int b = bid >> 4;
    const int h = bid & 15;
    const int tid = threadIdx.x;
    const int n  = tid >> 2;
    const int d0 = (tid & 3) * 8;
    const size_t base = ((size_t)(b * 64 + n)) * 512 + h * 32 + d0;

    {
        bf16x8 rq = *(const bf16x8*)(q + base);
        bf16x8 rk = *(const bf16x8*)(k + base);
        bf16x8 rv = *(const bf16x8*)(v + base);
#pragma unroll
        for (int t = 0; t < 8; ++t) {
            qs[n][d0 + t] = (float)rq[t];
            ks[n][d0 + t] = (float)rk[t];
            vs[n][d0 + t] = (float)rv[t];
        }
    }
    __syncthreads();

    {
        const int r  = tid >> 2;
        const int c0 = (tid & 3) * 16;
        const int rh = r >> 3, rw = r & 7;
        const float scale = 0.17677669529663687f;   // 1/sqrt(32)
#pragma unroll 4
        for (int cc = 0; cc < 16; ++cc) {
            const int c = c0 + cc;
            float s = 0.0f;
#pragma unroll
            for (int d = 0; d < 32; ++d) s += qs[r][d] * ks[c][d];
            const int ch = c >> 3, cw = c & 7;
            const int idx = (rh - ch + 7) * 15 + (rw - cw + 7);
            S[r][c] = s * scale + bias_table[idx * 16 + h];
        }
    }
    __syncthreads();

    if (tid < 64) {
        float m = -1e30f;
        for (int c = 0; c < 64; ++c) m = fmaxf(m, S[tid][c]);
        float sum = 0.0f;
        for (int c = 0; c < 64; ++c) { float e = __expf(S[tid][c] - m); S[tid][c] = e; sum += e; }
        float inv = 1.0f / sum;
        for (int c = 0; c < 64; ++c) S[tid][c] *= inv;
    }
    __syncthreads();

    {
        const int r = tid >> 2;
        float o[8] = {};
        for (int m = 0; m < 64; ++m) {
            const float sm = S[r][m];
#pragma unroll
            for (int t = 0; t < 8; ++t) o[t] += sm * vs[m][d0 + t];
        }
        bf16x8 ov;
#pragma unroll
        for (int t = 0; t < 8; ++t) ov[t] = (bf16)o[t];
        *(bf16x8*)(ctx + base) = ov;
    }
}

// ---------------------------------------------------------------------------
// ws layout (bf16 elements) — total 52,690,944 elems = 105.4 MB
// (<= 138.9 MB proven safe by rounds 2/3 bit-identical outputs):
//   0         WqT     512*512
//   262144    WvT     512*512
//   524288    WprojT  512*512
//   786432    WkT     512*3072  (row n = [Wk_base[:,n] | Wk_spline[:,n]])
//   2359296   xb      32768*512 (bf16 x)
//   19136512  q/ctx   32768*512
//   35913728  k       32768*512
// d_out (fp32, 67 MB) doubles as scratch: lower half swb (bf16 swish(x)),
// upper half v (bf16). Both dead before the final GEMM rewrites d_out.
// ---------------------------------------------------------------------------
extern "C" void kernel_launch(void* const* d_in, const int* in_sizes, int n_in,
                              void* d_out, int out_size, void* d_ws, size_t ws_size,
                              hipStream_t stream)
{
    const float* x       = (const float*)d_in[0];
    const float* Wq      = (const float*)d_in[1];
    const float* Wk_base = (const float*)d_in[2];
    const float* Wk_spl  = (const float*)d_in[3];
    const float* Wv      = (const float*)d_in[4];
    const float* Wproj   = (const float*)d_in[5];
    const float* bproj   = (const float*)d_in[6];
    const float* btab    = (const float*)d_in[7];

    bf16* ws  = (bf16*)d_ws;
    bf16* wqT = ws;
    bf16* wvT = ws + 262144;
    bf16* wpT = ws + 524288;
    bf16* wkT = ws + 786432;
    bf16* xb  = ws + 2359296;
    bf16* q   = ws + 19136512;
    bf16* kk  = ws + 35913728;
    bf16* swb = (bf16*)d_out;              // lower half of d_out
    bf16* vv  = (bf16*)d_out + 16777216;   // upper half of d_out
    bf16* ctx = q;                         // reuse q

    prep<<<8192, 256, 0, stream>>>(x, xb, swb, 16777216);

    transpose_k<<<1024, 256, 0, stream>>>(Wq,      wqT,       512,  512, 512,  262144);
    transpose_k<<<1024, 256, 0, stream>>>(Wv,      wvT,       512,  512, 512,  262144);
    transpose_k<<<1024, 256, 0, stream>>>(Wproj,   wpT,       512,  512, 512,  262144);
    transpose_k<<<1024, 256, 0, stream>>>(Wk_base, wkT,       512,  512, 3072, 262144);
    transpose_k<<<5120, 256, 0, stream>>>(Wk_spl,  wkT + 512, 2560, 512, 3072, 1310720);

    // Full-N tiling: grid = M/64 = 512 blocks, 512 threads.
    gemm_bt<0, false, bf16><<<512, 512, 0, stream>>>(xb,  nullptr, wqT, q,  32768, 512,  nullptr);
    gemm_bt<2, false, bf16><<<512, 512, 0, stream>>>(swb, x,       wkT, kk, 32768, 3072, nullptr);
    gemm_bt<0, false, bf16><<<512, 512, 0, stream>>>(xb,  nullptr, wvT, vv, 32768, 512,  nullptr);

    attn_kernel<<<8192, 256, 0, stream>>>(q, kk, vv, btab, ctx);

    gemm_bt<0, true, float><<<512, 512, 0, stream>>>(ctx, nullptr, wpT, (float*)d_out, 32768, 512, bproj);
}